// Round 1
// baseline (20054.736 us; speedup 1.0000x reference)
//
#include <hip/hip_runtime.h>
#include <hip/hip_cooperative_groups.h>
#include <stdint.h>

namespace cg = cooperative_groups;

// The np reference was generated with XLA-CPU-style FP contraction: the LIF
// recurrence MUST be fmaf(alpha, v, i) — verified bit-exact in round 4's
// designed experiment (separate mul/add flips 1-2 of 26.2M l1 decisions).
#pragma clang fp contract(off)

#define BB 128
#define TT 100
#define NN 2048
#define OO 512
#define DLY 10

#define ALPHA_F 0.90483741803595952f
#define DEC_F   0.95122942450071403f
#define OMD_F   0.048770575499285966f
#define A_P 1e-4f
#define A_M 1e-4f
#define THRV 0.02f
#define INVB 0.0078125f   // 1/128 exact

// ---- workspace layout (bytes) ----
#define OFF_MASK   ((size_t)0)          // u64 [BB][TT][32]  l1 spike bitmasks
#define OFF_HWT    ((size_t)3276800)    // f32 [NN][OO]      hw transposed
#define OFF_IEWT   ((size_t)7471104)    // f32 [OO][OO]      iew transposed, diag-masked
#define OFF_TR1    ((size_t)8519680)    // f32 [BB][NN]
#define OFF_TR2    ((size_t)9568256)    // f32 [BB][OO]
#define OFF_TRI    ((size_t)9830400)    // f32 [BB][OO]
#define OFF_V2     ((size_t)10092544)   // f32 [BB][OO]
#define OFF_VI     ((size_t)10354688)   // f32 [BB][OO]
#define OFF_BUF    ((size_t)10616832)   // f32 [BB][DLY][OO]
#define OFF_EIWD   ((size_t)13238272)   // f32 [OO]          eiw diagonal
#define OFF_ML2    ((size_t)13240320)   // f32 [2][OO]  sum_b l2 (exact ints)
#define OFF_MINH   ((size_t)13244416)   // f32 [2][OO]  sum_b inh
#define OFF_MTR2S  ((size_t)13248512)   // f32 [2][OO]  mean(tr2) state
#define OFF_MTRIS  ((size_t)13252608)   // f32 [2][OO]  mean(tri) state
#define OFF_COLS   ((size_t)13256704)   // f32 [2][OO]  column sums of iewT
#define OFF_FLAGS  ((size_t)13260800)   // u32 [4]: 0=anyL2spike
#define WS_NEED    ((size_t)13260816)

#define PTRS(ws) \
  unsigned long long* mask = (unsigned long long*)((ws) + OFF_MASK); \
  float* hwT  = (float*)((ws) + OFF_HWT);  \
  float* iewT = (float*)((ws) + OFF_IEWT); \
  float* tr1  = (float*)((ws) + OFF_TR1);  \
  float* tr2  = (float*)((ws) + OFF_TR2);  \
  float* tri  = (float*)((ws) + OFF_TRI);  \
  float* v2   = (float*)((ws) + OFF_V2);   \
  float* vi   = (float*)((ws) + OFF_VI);   \
  float* buf  = (float*)((ws) + OFF_BUF);  \
  float* eiwd = (float*)((ws) + OFF_EIWD); \
  float* ml2  = (float*)((ws) + OFF_ML2);  \
  float* minh = (float*)((ws) + OFF_MINH); \
  float* m2s  = (float*)((ws) + OFF_MTR2S);\
  float* m3s  = (float*)((ws) + OFF_MTRIS);\
  float* cols = (float*)((ws) + OFF_COLS); \
  unsigned* flags = (unsigned*)((ws) + OFF_FLAGS); \
  (void)mask;(void)hwT;(void)iewT;(void)tr1;(void)tr2;(void)tri;(void)v2;(void)vi; \
  (void)buf;(void)eiwd;(void)ml2;(void)minh;(void)m2s;(void)m3s;(void)cols;(void)flags;

// Zero the flag words before kA (ws arrives poisoned 0xAA).
__global__ void kZ(uint8_t* __restrict__ ws) {
  PTRS(ws);
  if (threadIdx.x < 4) flags[threadIdx.x] = 0u;
}

// ---------------------------------------------------------------------------
// Kernel A: full l1/v1 path for all t (weight-independent) with the verified
// FMA recurrence; spike bitmasks; all workspace init.
// Round change: t-loop unrolled x4 so 4 independent x-loads are in flight on
// the serial v-chain (was VALUBusy 4%, 16 VGPR, one load in flight).
// ---------------------------------------------------------------------------
__global__ __launch_bounds__(256) void kA(
    const float* __restrict__ x, const float* __restrict__ w_in,
    const float* __restrict__ hid, const float* __restrict__ eiw_in,
    const float* __restrict__ iew_in, float* __restrict__ out,
    uint8_t* __restrict__ ws)
{
#pragma clang fp contract(off)
  const int bx = blockIdx.x, tid = threadIdx.x;
  PTRS(ws);

  if (bx < 1024) {
    const int b = bx >> 3;
    const int n = ((bx & 7) << 8) + tid;
    const float wd = w_in[(size_t)n * NN + n];      // input_weight diagonal
    const float* xp = x + ((size_t)b * TT) * NN + n;
    float* op = out + ((size_t)b * TT) * NN + n;
    const int word = n >> 6;
    const bool lane0 = ((tid & 63) == 0);
    unsigned long long* mrow = mask + ((size_t)b * TT) * 32 + word;
    float v = 0.f;
    for (int t = 0; t < TT; t += 4) {               // TT = 100 = 4*25 exact
      float xv0 = xp[(size_t)(t    ) * NN];
      float xv1 = xp[(size_t)(t + 1) * NN];
      float xv2 = xp[(size_t)(t + 2) * NN];
      float xv3 = xp[(size_t)(t + 3) * NN];
      // arithmetic per sub-step identical to the verified scalar loop
      v = fmaf(ALPHA_F, v, wd * xv0);
      bool s0 = (v > THRV); op[(size_t)(t    ) * NN] = s0 ? 1.f : 0.f; if (s0) v = 0.f;
      unsigned long long m0 = __ballot(s0);
      v = fmaf(ALPHA_F, v, wd * xv1);
      bool s1 = (v > THRV); op[(size_t)(t + 1) * NN] = s1 ? 1.f : 0.f; if (s1) v = 0.f;
      unsigned long long m1 = __ballot(s1);
      v = fmaf(ALPHA_F, v, wd * xv2);
      bool s2 = (v > THRV); op[(size_t)(t + 2) * NN] = s2 ? 1.f : 0.f; if (s2) v = 0.f;
      unsigned long long m2 = __ballot(s2);
      v = fmaf(ALPHA_F, v, wd * xv3);
      bool s3 = (v > THRV); op[(size_t)(t + 3) * NN] = s3 ? 1.f : 0.f; if (s3) v = 0.f;
      unsigned long long m3 = __ballot(s3);
      if (lane0) {
        mrow[(size_t)(t    ) * 32] = m0;
        mrow[(size_t)(t + 1) * 32] = m1;
        mrow[(size_t)(t + 2) * 32] = m2;
        mrow[(size_t)(t + 3) * 32] = m3;
      }
    }
  } else {
    const int idx = (bx - 1024) * 256 + tid;        // 0..262143
    #pragma unroll
    for (int k = 0; k < 4; ++k) {                   // hwT[n][q] = hid[q][n]
      int e = idx + k * 262144;
      int n = e & (NN - 1);
      int q = e >> 11;
      hwT[(size_t)n * OO + q] = hid[(size_t)q * NN + n];
    }
    { int p = idx >> 9, q = idx & (OO - 1);         // iewT[p][q] = iew[q][p], diag 0
      iewT[idx] = (p == q) ? 0.f : iew_in[(size_t)q * OO + p]; }
    tr1[idx] = 0.f;
    if (idx < BB * OO) { tr2[idx]=0.f; tri[idx]=0.f; v2[idx]=0.f; vi[idx]=0.f; }
    #pragma unroll
    for (int k = 0; k < 3; ++k) { int e = idx + k * 262144; if (e < BB*DLY*OO) buf[e]=0.f; }
    if (idx < OO) eiwd[idx] = eiw_in[(size_t)idx * OO + idx];
    if (idx < 2*OO) { ml2[idx]=0.f; minh[idx]=0.f; m2s[idx]=0.f; m3s[idx]=0.f; }
    if (idx < OO) {                                 // cols slot0 = masked row-sums of iew_in
      float sacc = 0.f;
      for (int p = 0; p < OO; ++p) if (p != idx) sacc += iew_in[(size_t)idx * OO + p];
      cols[idx] = sacc; cols[OO + idx] = 0.f;
    }
  }
}

// ---------------------------------------------------------------------------
// Persistent cooperative kernel: the entire 100-step loop in ONE dispatch.
// Grid 256 blocks x 512 threads, 1 block/CU (131 KB LDS). Per step:
//   phase 1 == old kStep1 (blocks 0..127 O-path, 128..255 tr1-from-bitmask)
//   grid.sync()
//   phase 2 == old kStep2 (two 64x64 tiles per block, one per 256-thread
//              half; diag task on block 160's lower half)
//   grid.sync()
// Replaces 200 dependent dispatches (launch + drain + cache-flush each) with
// 200 grid barriers. All per-(b,q) arithmetic is bit-identical to the old
// kernels; only already-nondeterministic orderings (compaction order,
// cols atomics) changed.
// ---------------------------------------------------------------------------
__global__ __launch_bounds__(512) void kLoop(
    const int* __restrict__ train_p, float* __restrict__ out,
    uint8_t* __restrict__ ws)
{
#pragma clang fp contract(off)
  const int bx = blockIdx.x, tid = threadIdx.x;
  PTRS(ws);
  const int train = *train_p;
  cg::grid_group grid = cg::this_grid();

  __shared__ union SmemU {
    struct { float s1[2][BB * 64]; float s2[2][BB * 64]; } p2;   // 128 KiB
    struct { unsigned long long sm[32]; int sidx[NN]; short szer[OO]; } p1;
  } U;
  __shared__ int scnt, zcnt, anyc;

  for (int t = 0; t < TT; ++t) {
    const int s = t & 1, tm = t % DLY;
    const int se = train ? s : 0;   // eval: cols never cycles, use slot 0

    // ================= phase 1 =================
    if (bx < BB) {
      const int b = bx, q = tid, lane = tid & 63;
      if (tid == 0) { scnt = 0; zcnt = 0; anyc = 0; }
      if (tid < 32) U.p1.sm[tid] = mask[((size_t)b * TT + t) * 32 + tid];
      float bv = buf[((size_t)b * DLY + tm) * OO + q];
      float c = cols[se * OO + q];
      __syncthreads();
      if (c != 0.f) anyc = 1;
      // ballot-based compaction: 1 LDS atomic per wave instead of per spike
      #pragma unroll
      for (int k = 0; k < 4; ++k) {
        int n = (k << 9) + tid;
        bool sp = (U.p1.sm[n >> 6] >> (n & 63)) & 1ull;
        unsigned long long mb = __ballot(sp);
        int base = 0;
        if (lane == 0 && mb) base = atomicAdd(&scnt, __popcll(mb));
        base = __shfl(base, 0, 64);
        if (sp) U.p1.sidx[base + __popcll(mb & ((1ull << lane) - 1ull))] = n;
      }
      {
        bool z = (bv == 0.f);
        unsigned long long mz = __ballot(z);
        int bz = 0;
        if (lane == 0 && mz) bz = atomicAdd(&zcnt, __popcll(mz));
        bz = __shfl(bz, 0, 64);
        if (z) U.p1.szer[bz + __popcll(mz & ((1ull << lane) - 1ull))] = (short)q;
      }
      if (train && bx == 0) {                       // cycle double-buffered slots
        cols[(s ^ 1) * OO + q] = 0.f;
        ml2 [(s ^ 1) * OO + q] = 0.f;
        minh[(s ^ 1) * OO + q] = 0.f;
      }
      __syncthreads();
      // l1v[b,q] = sum over spiking n of hwT[n][q] — serial add order kept,
      // unroll x8 only widens the load window (8 loads in flight)
      float l1v = 0.f;
      { const int cnt = scnt;
        int k = 0;
        for (; k + 8 <= cnt; k += 8) {
          float h0=hwT[(size_t)U.p1.sidx[k  ]*OO+q], h1=hwT[(size_t)U.p1.sidx[k+1]*OO+q];
          float h2=hwT[(size_t)U.p1.sidx[k+2]*OO+q], h3=hwT[(size_t)U.p1.sidx[k+3]*OO+q];
          float h4=hwT[(size_t)U.p1.sidx[k+4]*OO+q], h5=hwT[(size_t)U.p1.sidx[k+5]*OO+q];
          float h6=hwT[(size_t)U.p1.sidx[k+6]*OO+q], h7=hwT[(size_t)U.p1.sidx[k+7]*OO+q];
          l1v += h0; l1v += h1; l1v += h2; l1v += h3;
          l1v += h4; l1v += h5; l1v += h6; l1v += h7;
        }
        for (; k < cnt; ++k) l1v += hwT[(size_t)U.p1.sidx[k]*OO+q];
      }
      if (!train) l1v = 0.2f * l1v;
      // inh_out = colsum - sum over buf==0 rows (exactly 0 while iew == 0)
      float inh_o = 0.f;
      if (anyc) {
        float acc2 = c; const int zc = zcnt;
        int k = 0;
        for (; k + 4 <= zc; k += 4) {
          int z0=U.p1.szer[k], z1=U.p1.szer[k+1], z2=U.p1.szer[k+2], z3=U.p1.szer[k+3];
          acc2 -= iewT[(size_t)z0*OO+q]; acc2 -= iewT[(size_t)z1*OO+q];
          acc2 -= iewT[(size_t)z2*OO+q]; acc2 -= iewT[(size_t)z3*OO+q];
        }
        for (; k < zc; ++k) acc2 -= iewT[(size_t)U.p1.szer[k]*OO+q];
        inh_o = acc2;
      }
      // l2 neuron (FMA recurrence; margins robust)
      const int bq = b * OO + q;
      float i2  = l1v - inh_o;
      float v2v = fmaf(ALPHA_F, v2[bq], i2);
      bool l2 = (v2v > THRV);
      v2[bq] = l2 ? 0.f : v2v;
      out[(size_t)BB*TT*NN + ((size_t)b * TT + t) * OO + q] = l2 ? 1.f : 0.f;
      // inh neuron: inh_in = l2 * eiw_diag[q]
      float ii  = l2 ? eiwd[q] : 0.f;
      float viv = fmaf(ALPHA_F, vi[bq], ii);
      bool ih = (viv > THRV);
      vi[bq] = ih ? 0.f : viv;
      buf[((size_t)b * DLY + tm) * OO + q] = ih ? 1.f : 0.f;
      if (train) {
        float l2f = l2 ? 1.f : 0.f, ihf = ih ? 1.f : 0.f;
        float d2 = DEC_F * tr2[bq]; tr2[bq] = d2 + OMD_F * l2f;
        float d3 = DEC_F * tri[bq]; tri[bq] = d3 + OMD_F * ihf;
        if (l2) { atomicAdd(&ml2[s * OO + q], 1.f); flags[0] = 1u; }
        if (ih) { atomicAdd(&minh[s * OO + q], 1.f); }
      }
    } else if (train) {
      // tr1 update for batch b from the spike bitmask (no out re-read)
      const int b = bx - BB;
      const unsigned long long* mrow = mask + ((size_t)b * TT + t) * 32;
      float* tp = tr1 + (size_t)b * NN;
      #pragma unroll
      for (int k = 0; k < 4; ++k) {
        int n = (k << 9) + tid;
        float l1 = ((mrow[n >> 6] >> (n & 63)) & 1ull) ? 1.f : 0.f;
        float d = DEC_F * tp[n];
        tp[n] = d + OMD_F * l1;
      }
    }
    __threadfence();
    grid.sync();

    // ================= phase 2 =================
    if (train) {
      const int hsel = tid >> 8, ltid = tid & 255;
      const int halfId = (bx << 1) + hsel;           // 0..511 half-slots
      const bool live = (halfId < 320) && (flags[0] != 0u);
      const bool isHW = (halfId < 256);
      const int e  = isHW ? halfId : (halfId - 256);
      const int pt = e >> 3, qt = e & 7;
      float* s1p = U.p2.s1[hsel];
      float* s2p = U.p2.s2[hsel];
      if (live) {
        const float* Apre = isHW ? tr1 : tri;        // pre-trace slab
        const int preStride = isHW ? NN : OO;
        for (int it = 0; it < 8; ++it) {             // float4 staging
          int ee = (it << 8) + ltid;                 // 2048 float4 = 8192 floats
          int bb = ee >> 4, i = (ee & 15) << 2;
          *(float4*)&s1p[(bb << 6) + i] =
              *(const float4*)&Apre[(size_t)bb * preStride + (pt << 6) + i];
          *(float4*)&s2p[(bb << 6) + i] =
              *(const float4*)&tr2[(bb << 9) + (qt << 6) + i];
        }
      }
      __syncthreads();
      if (live) {
        const int tp = ltid >> 4, tq = ltid & 15;
        float acc[4][4] = {{0.f,0.f,0.f,0.f},{0.f,0.f,0.f,0.f},
                           {0.f,0.f,0.f,0.f},{0.f,0.f,0.f,0.f}};
        for (int b = 0; b < BB; ++b) {
          float4 av = *(const float4*)&s1p[(b << 6) + (tp << 2)];
          float4 cv = *(const float4*)&s2p[(b << 6) + (tq << 2)];
          acc[0][0] = fmaf(av.x, cv.x, acc[0][0]);
          acc[0][1] = fmaf(av.x, cv.y, acc[0][1]);
          acc[0][2] = fmaf(av.x, cv.z, acc[0][2]);
          acc[0][3] = fmaf(av.x, cv.w, acc[0][3]);
          acc[1][0] = fmaf(av.y, cv.x, acc[1][0]);
          acc[1][1] = fmaf(av.y, cv.y, acc[1][1]);
          acc[1][2] = fmaf(av.y, cv.z, acc[1][2]);
          acc[1][3] = fmaf(av.y, cv.w, acc[1][3]);
          acc[2][0] = fmaf(av.z, cv.x, acc[2][0]);
          acc[2][1] = fmaf(av.z, cv.y, acc[2][1]);
          acc[2][2] = fmaf(av.z, cv.z, acc[2][2]);
          acc[2][3] = fmaf(av.z, cv.w, acc[2][3]);
          acc[3][0] = fmaf(av.w, cv.x, acc[3][0]);
          acc[3][1] = fmaf(av.w, cv.y, acc[3][1]);
          acc[3][2] = fmaf(av.w, cv.z, acc[3][2]);
          acc[3][3] = fmaf(av.w, cv.w, acc[3][3]);
        }
        float mq[4];
        #pragma unroll
        for (int j = 0; j < 4; ++j) {    // mean(tr2_t) via exact binary-spike recurrence
          int q = (qt << 6) + (tq << 2) + j;
          mq[j] = DEC_F * m2s[s * OO + q] + OMD_F * (ml2[s * OO + q] * INVB);
        }
        if (isHW) {
          #pragma unroll
          for (int i = 0; i < 4; ++i) {
            size_t p = (size_t)((pt << 6) + (tp << 2) + i);
            float4* hp = (float4*)&hwT[p * OO + (qt << 6) + (tq << 2)];
            float4 o4 = *hp;
            float4 nv;
            nv.x = o4.x + (A_P * (acc[i][0] * INVB) - A_M * o4.x * mq[0]);
            nv.y = o4.y + (A_P * (acc[i][1] * INVB) - A_M * o4.y * mq[1]);
            nv.z = o4.z + (A_P * (acc[i][2] * INVB) - A_M * o4.z * mq[2]);
            nv.w = o4.w + (A_P * (acc[i][3] * INVB) - A_M * o4.w * mq[3]);
            *hp = nv;
          }
        } else {
          float csum[4] = {0.f,0.f,0.f,0.f};
          #pragma unroll
          for (int i = 0; i < 4; ++i) {
            int p = (pt << 6) + (tp << 2) + i;
            #pragma unroll
            for (int j = 0; j < 4; ++j) {
              int q = (qt << 6) + (tq << 2) + j;
              float* wp = &iewT[(size_t)p * OO + q];
              float oldv = *wp;
              float nv = (p == q) ? 0.f
                                  : (oldv + (A_P * (acc[i][j] * INVB) - A_M * oldv * mq[j]));
              *wp = nv;
              csum[j] += nv;
            }
          }
          #pragma unroll
          for (int j = 0; j < 4; ++j)
            atomicAdd(&cols[(s ^ 1) * OO + ((qt << 6) + (tq << 2) + j)], csum[j]);
        }
      } else if (halfId == 320) {
        // eiw diagonal + mean-state slot cycling (runs every step)
        for (int k = 0; k < 2; ++k) {
          int q = (k << 8) + ltid;
          float m2v = DEC_F * m2s[s*OO+q] + OMD_F * (ml2[s*OO+q] * INVB);
          float m3v = DEC_F * m3s[s*OO+q] + OMD_F * (minh[s*OO+q] * INVB);
          m2s[(s^1)*OO+q] = m2v;
          m3s[(s^1)*OO+q] = m3v;
          float hd = 0.f;
          for (int b = 0; b < BB; ++b) hd = fmaf(tri[b*OO+q], tr2[b*OO+q], hd);
          hd *= INVB;
          float oldv = eiwd[q];
          eiwd[q] = oldv + (A_P * hd - A_M * oldv * m3v);
        }
      }
    }
    __threadfence();
    grid.sync();
  }
}

// ---------------------------------------------------------------------------
// Fallback step kernels (verified baseline path) — used only if the
// cooperative launch is rejected (e.g. capture incompatibility).
// ---------------------------------------------------------------------------
__global__ __launch_bounds__(512) void kStep1(
    const int* __restrict__ train_p, float* __restrict__ out,
    uint8_t* __restrict__ ws, int t)
{
#pragma clang fp contract(off)
  const int bx = blockIdx.x, tid = threadIdx.x;
  const int s = t & 1, tm = t % DLY;
  PTRS(ws);
  const int train = *train_p;
  const int se = train ? s : 0;

  if (bx < BB) {
    __shared__ unsigned long long sm[32];
    __shared__ int sidx[NN];
    __shared__ short szer[OO];
    __shared__ int scnt, zcnt, anyc;
    const int b = bx, q = tid;
    if (tid == 0) { scnt = 0; zcnt = 0; anyc = 0; }
    if (tid < 32) sm[tid] = mask[((size_t)b * TT + t) * 32 + tid];
    float bv = buf[((size_t)b * DLY + tm) * OO + q];
    float c = cols[se * OO + q];
    __syncthreads();
    if (c != 0.f) anyc = 1;
    #pragma unroll
    for (int k = 0; k < 4; ++k) {
      int n = (k << 9) + tid;
      if ((sm[n >> 6] >> (n & 63)) & 1ull) { int pos = atomicAdd(&scnt, 1); sidx[pos] = n; }
    }
    if (bv == 0.f) { int pz = atomicAdd(&zcnt, 1); szer[pz] = (short)q; }
    if (train && bx == 0) {
      cols[(s ^ 1) * OO + q] = 0.f;
      ml2 [(s ^ 1) * OO + q] = 0.f;
      minh[(s ^ 1) * OO + q] = 0.f;
    }
    __syncthreads();
    float l1v = 0.f;
    { const int cnt = scnt;
      int k = 0;
      for (; k + 4 <= cnt; k += 4) {
        int n0=sidx[k], n1=sidx[k+1], n2=sidx[k+2], n3=sidx[k+3];
        float h0=hwT[(size_t)n0*OO+q], h1=hwT[(size_t)n1*OO+q];
        float h2=hwT[(size_t)n2*OO+q], h3=hwT[(size_t)n3*OO+q];
        l1v += h0; l1v += h1; l1v += h2; l1v += h3;
      }
      for (; k < cnt; ++k) l1v += hwT[(size_t)sidx[k]*OO+q];
    }
    if (!train) l1v = 0.2f * l1v;
    float inh_o = 0.f;
    if (anyc) {
      float acc = c; const int zc = zcnt;
      int k = 0;
      for (; k + 4 <= zc; k += 4) {
        int p0=szer[k], p1=szer[k+1], p2=szer[k+2], p3=szer[k+3];
        acc -= iewT[(size_t)p0*OO+q]; acc -= iewT[(size_t)p1*OO+q];
        acc -= iewT[(size_t)p2*OO+q]; acc -= iewT[(size_t)p3*OO+q];
      }
      for (; k < zc; ++k) acc -= iewT[(size_t)szer[k]*OO+q];
      inh_o = acc;
    }
    const int bq = b * OO + q;
    float i2  = l1v - inh_o;
    float v2v = fmaf(ALPHA_F, v2[bq], i2);
    bool l2 = (v2v > THRV);
    v2[bq] = l2 ? 0.f : v2v;
    out[(size_t)BB*TT*NN + ((size_t)b * TT + t) * OO + q] = l2 ? 1.f : 0.f;
    float ii  = l2 ? eiwd[q] : 0.f;
    float viv = fmaf(ALPHA_F, vi[bq], ii);
    bool ih = (viv > THRV);
    vi[bq] = ih ? 0.f : viv;
    buf[((size_t)b * DLY + tm) * OO + q] = ih ? 1.f : 0.f;
    if (train) {
      float l2f = l2 ? 1.f : 0.f, ihf = ih ? 1.f : 0.f;
      float d2 = DEC_F * tr2[bq]; tr2[bq] = d2 + OMD_F * l2f;
      float d3 = DEC_F * tri[bq]; tri[bq] = d3 + OMD_F * ihf;
      if (l2) { atomicAdd(&ml2[s * OO + q], 1.f); flags[0] = 1u; }
      if (ih) { atomicAdd(&minh[s * OO + q], 1.f); }
    }
  } else {
    const int b = bx - BB;
    if (train) {
      const float* lp = out + ((size_t)b * TT + t) * NN;
      float* tp = tr1 + (size_t)b * NN;
      #pragma unroll
      for (int k = 0; k < 4; ++k) {
        int n = (k << 9) + tid;
        float d = DEC_F * tp[n];
        tp[n] = d + OMD_F * lp[n];
      }
    }
  }
}

__global__ __launch_bounds__(256) void kStep2(
    const int* __restrict__ train_p, uint8_t* __restrict__ ws, int t)
{
#pragma clang fp contract(off)
  const int bx = blockIdx.x, tid = threadIdx.x;
  const int s = t & 1;
  PTRS(ws);
  if (!*train_p) return;

  if (bx < 320) {
    if (!flags[0]) return;
    const bool isHW = (bx < 256);
    const int e  = isHW ? bx : (bx - 256);
    const int pt = e >> 3, qt = e & 7;
    __shared__ float s1[BB * 64];
    __shared__ float s2[BB * 64];
    const float* Apre = isHW ? tr1 : tri;
    const int preStride = isHW ? NN : OO;
    for (int it = 0; it < 32; ++it) {
      int ee = it * 256 + tid;
      int b = ee >> 6, i = ee & 63;
      s1[ee] = Apre[(size_t)b * preStride + pt * 64 + i];
      s2[ee] = tr2[b * OO + qt * 64 + i];
    }
    __syncthreads();
    const int tp = tid >> 4, tq = tid & 15;
    float acc[4][4] = {{0.f,0.f,0.f,0.f},{0.f,0.f,0.f,0.f},{0.f,0.f,0.f,0.f},{0.f,0.f,0.f,0.f}};
    for (int b = 0; b < BB; ++b) {
      float4 av = *(const float4*)&s1[b * 64 + tp * 4];
      float4 cv = *(const float4*)&s2[b * 64 + tq * 4];
      acc[0][0] = fmaf(av.x, cv.x, acc[0][0]);
      acc[0][1] = fmaf(av.x, cv.y, acc[0][1]);
      acc[0][2] = fmaf(av.x, cv.z, acc[0][2]);
      acc[0][3] = fmaf(av.x, cv.w, acc[0][3]);
      acc[1][0] = fmaf(av.y, cv.x, acc[1][0]);
      acc[1][1] = fmaf(av.y, cv.y, acc[1][1]);
      acc[1][2] = fmaf(av.y, cv.z, acc[1][2]);
      acc[1][3] = fmaf(av.y, cv.w, acc[1][3]);
      acc[2][0] = fmaf(av.z, cv.x, acc[2][0]);
      acc[2][1] = fmaf(av.z, cv.y, acc[2][1]);
      acc[2][2] = fmaf(av.z, cv.z, acc[2][2]);
      acc[2][3] = fmaf(av.z, cv.w, acc[2][3]);
      acc[3][0] = fmaf(av.w, cv.x, acc[3][0]);
      acc[3][1] = fmaf(av.w, cv.y, acc[3][1]);
      acc[3][2] = fmaf(av.w, cv.z, acc[3][2]);
      acc[3][3] = fmaf(av.w, cv.w, acc[3][3]);
    }
    float mq[4];
    #pragma unroll
    for (int j = 0; j < 4; ++j) {
      int q = qt * 64 + tq * 4 + j;
      mq[j] = DEC_F * m2s[s * OO + q] + OMD_F * (ml2[s * OO + q] * INVB);
    }
    if (isHW) {
      #pragma unroll
      for (int i = 0; i < 4; ++i) {
        size_t p = (size_t)(pt * 64 + tp * 4 + i);
        #pragma unroll
        for (int j = 0; j < 4; ++j) {
          int q = qt * 64 + tq * 4 + j;
          float* hp = &hwT[p * OO + q];
          float old = *hp;
          *hp = old + (A_P * (acc[i][j] * INVB) - A_M * old * mq[j]);
        }
      }
    } else {
      float csum[4] = {0.f,0.f,0.f,0.f};
      #pragma unroll
      for (int i = 0; i < 4; ++i) {
        int p = pt * 64 + tp * 4 + i;
        #pragma unroll
        for (int j = 0; j < 4; ++j) {
          int q = qt * 64 + tq * 4 + j;
          float* wp = &iewT[(size_t)p * OO + q];
          float old = *wp;
          float nv = (p == q) ? 0.f
                              : (old + (A_P * (acc[i][j] * INVB) - A_M * old * mq[j]));
          *wp = nv;
          csum[j] += nv;
        }
      }
      #pragma unroll
      for (int j = 0; j < 4; ++j)
        atomicAdd(&cols[(s ^ 1) * OO + (qt * 64 + tq * 4 + j)], csum[j]);
    }
  } else {
    for (int k = 0; k < 2; ++k) {
      int q = k * 256 + tid;
      float m2v = DEC_F * m2s[s*OO+q] + OMD_F * (ml2[s*OO+q] * INVB);
      float m3v = DEC_F * m3s[s*OO+q] + OMD_F * (minh[s*OO+q] * INVB);
      m2s[(s^1)*OO+q] = m2v;
      m3s[(s^1)*OO+q] = m3v;
      float hd = 0.f;
      for (int b = 0; b < BB; ++b) hd = fmaf(tri[b*OO+q], tr2[b*OO+q], hd);
      hd *= INVB;
      float old = eiwd[q];
      eiwd[q] = old + (A_P * hd - A_M * old * m3v);
    }
  }
}

extern "C" void kernel_launch(void* const* d_in, const int* in_sizes, int n_in,
                              void* d_out, int out_size, void* d_ws, size_t ws_size,
                              hipStream_t stream) {
  const float* x     = (const float*)d_in[0];
  const float* w_in  = (const float*)d_in[1];
  const float* hid   = (const float*)d_in[2];
  const float* eiw   = (const float*)d_in[3];
  const float* iew   = (const float*)d_in[4];
  const int*   train = (const int*)d_in[5];
  float* out = (float*)d_out;
  uint8_t* ws = (uint8_t*)d_ws;
  (void)in_sizes; (void)n_in; (void)out_size; (void)ws_size;

  hipLaunchKernelGGL(kZ, dim3(1), dim3(64), 0, stream, ws);
  hipLaunchKernelGGL(kA, dim3(2048), dim3(256), 0, stream, x, w_in, hid, eiw, iew, out, ws);

  void* kargs[3];
  kargs[0] = (void*)&train;
  kargs[1] = (void*)&out;
  kargs[2] = (void*)&ws;
  hipError_t err = hipLaunchCooperativeKernel(
      reinterpret_cast<const void*>(&kLoop), dim3(256), dim3(512),
      kargs, 0, stream);
  if (err != hipSuccess) {
    // Fallback: proven per-step dispatch path.
    for (int t = 0; t < TT; ++t) {
      hipLaunchKernelGGL(kStep1, dim3(256), dim3(512), 0, stream, train, out, ws, t);
      hipLaunchKernelGGL(kStep2, dim3(321), dim3(256), 0, stream, train, ws, t);
    }
  }
}

// Round 2
// 5040.645 us; speedup vs baseline: 3.9786x; 3.9786x over previous
//
#include <hip/hip_runtime.h>
#include <stdint.h>

// The np reference was generated with XLA-CPU-style FP contraction: the LIF
// recurrence MUST be fmaf(alpha, v, i) — verified bit-exact in round 4's
// designed experiment (separate mul/add flips 1-2 of 26.2M l1 decisions).
#pragma clang fp contract(off)

#define BB 128
#define TT 100
#define NN 2048
#define OO 512
#define DLY 10

#define ALPHA_F 0.90483741803595952f
#define DEC_F   0.95122942450071403f
#define OMD_F   0.048770575499285966f
#define A_P 1e-4f
#define A_M 1e-4f
#define THRV 0.02f
#define INVB 0.0078125f   // 1/128 exact

// ---- workspace layout (bytes) ----
#define OFF_MASK   ((size_t)0)          // u64 [BB][TT][32]  l1 spike bitmasks
#define OFF_HWT    ((size_t)3276800)    // f32 [NN][OO]      hw transposed
#define OFF_IEWT   ((size_t)7471104)    // f32 [OO][OO]      iew transposed, diag-masked
#define OFF_TR1    ((size_t)8519680)    // f32 [BB][NN]
#define OFF_TR2    ((size_t)9568256)    // f32 [BB][OO]
#define OFF_TRI    ((size_t)9830400)    // f32 [BB][OO]
#define OFF_V2     ((size_t)10092544)   // f32 [BB][OO]
#define OFF_VI     ((size_t)10354688)   // f32 [BB][OO]
#define OFF_BUF    ((size_t)10616832)   // f32 [BB][DLY][OO]
#define OFF_EIWD   ((size_t)13238272)   // f32 [OO]          eiw diagonal
#define OFF_ML2    ((size_t)13240320)   // f32 [2][OO]  sum_b l2 (exact ints)
#define OFF_MINH   ((size_t)13244416)   // f32 [2][OO]  sum_b inh
#define OFF_MTR2S  ((size_t)13248512)   // f32 [2][OO]  mean(tr2) state
#define OFF_MTRIS  ((size_t)13252608)   // f32 [2][OO]  mean(tri) state
#define OFF_COLS   ((size_t)13256704)   // f32 [2][OO]  column sums of iewT
#define OFF_FLAGS  ((size_t)13260800)   // u32 [4]: 0=anyL2spike
#define WS_NEED    ((size_t)13260816)

#define PTRS(ws) \
  unsigned long long* mask = (unsigned long long*)((ws) + OFF_MASK); \
  float* hwT  = (float*)((ws) + OFF_HWT);  \
  float* iewT = (float*)((ws) + OFF_IEWT); \
  float* tr1  = (float*)((ws) + OFF_TR1);  \
  float* tr2  = (float*)((ws) + OFF_TR2);  \
  float* tri  = (float*)((ws) + OFF_TRI);  \
  float* v2   = (float*)((ws) + OFF_V2);   \
  float* vi   = (float*)((ws) + OFF_VI);   \
  float* buf  = (float*)((ws) + OFF_BUF);  \
  float* eiwd = (float*)((ws) + OFF_EIWD); \
  float* ml2  = (float*)((ws) + OFF_ML2);  \
  float* minh = (float*)((ws) + OFF_MINH); \
  float* m2s  = (float*)((ws) + OFF_MTR2S);\
  float* m3s  = (float*)((ws) + OFF_MTRIS);\
  float* cols = (float*)((ws) + OFF_COLS); \
  unsigned* flags = (unsigned*)((ws) + OFF_FLAGS); \
  (void)mask;(void)hwT;(void)iewT;(void)tr1;(void)tr2;(void)tri;(void)v2;(void)vi; \
  (void)buf;(void)eiwd;(void)ml2;(void)minh;(void)m2s;(void)m3s;(void)cols;(void)flags;

// Zero the flag words before kA (ws arrives poisoned 0xAA).
__global__ void kZ(uint8_t* __restrict__ ws) {
  PTRS(ws);
  if (threadIdx.x < 4) flags[threadIdx.x] = 0u;
}

// ---------------------------------------------------------------------------
// Kernel A: full l1/v1 path for all t (weight-independent) with the verified
// FMA recurrence; spike bitmasks; all workspace init.
// Round change: t-loop software-pipelined x8 — 8 independent x-loads in
// flight on the serial v-chain (was VALUBusy 4%, 16 VGPR, 1 load in flight).
// Per-substep arithmetic is IDENTICAL to the verified scalar loop.
// ---------------------------------------------------------------------------
__global__ __launch_bounds__(256) void kA(
    const float* __restrict__ x, const float* __restrict__ w_in,
    const float* __restrict__ hid, const float* __restrict__ eiw_in,
    const float* __restrict__ iew_in, float* __restrict__ out,
    uint8_t* __restrict__ ws)
{
#pragma clang fp contract(off)
  const int bx = blockIdx.x, tid = threadIdx.x;
  PTRS(ws);

  if (bx < 1024) {
    const int b = bx >> 3;
    const int n = ((bx & 7) << 8) + tid;
    const float wd = w_in[(size_t)n * NN + n];      // input_weight diagonal
    const float* xp = x + ((size_t)b * TT) * NN + n;
    float* op = out + ((size_t)b * TT) * NN + n;
    const int word = n >> 6;
    const bool lane0 = ((tid & 63) == 0);
    unsigned long long* mrow = mask + ((size_t)b * TT) * 32 + word;
    float v = 0.f;
    int t = 0;
    for (; t + 8 <= TT; t += 8) {                   // 12 full groups of 8
      float xv[8];
      #pragma unroll
      for (int j = 0; j < 8; ++j) xv[j] = xp[(size_t)(t + j) * NN];
      unsigned long long mm[8];
      #pragma unroll
      for (int j = 0; j < 8; ++j) {
        v = fmaf(ALPHA_F, v, wd * xv[j]);
        bool sj = (v > THRV);
        op[(size_t)(t + j) * NN] = sj ? 1.f : 0.f;
        if (sj) v = 0.f;
        mm[j] = __ballot(sj);
      }
      if (lane0) {
        #pragma unroll
        for (int j = 0; j < 8; ++j) mrow[(size_t)(t + j) * 32] = mm[j];
      }
    }
    for (; t + 4 <= TT; t += 4) {                   // tail group of 4
      float xv[4];
      #pragma unroll
      for (int j = 0; j < 4; ++j) xv[j] = xp[(size_t)(t + j) * NN];
      unsigned long long mm[4];
      #pragma unroll
      for (int j = 0; j < 4; ++j) {
        v = fmaf(ALPHA_F, v, wd * xv[j]);
        bool sj = (v > THRV);
        op[(size_t)(t + j) * NN] = sj ? 1.f : 0.f;
        if (sj) v = 0.f;
        mm[j] = __ballot(sj);
      }
      if (lane0) {
        #pragma unroll
        for (int j = 0; j < 4; ++j) mrow[(size_t)(t + j) * 32] = mm[j];
      }
    }
  } else {
    const int idx = (bx - 1024) * 256 + tid;        // 0..262143
    #pragma unroll
    for (int k = 0; k < 4; ++k) {                   // hwT[n][q] = hid[q][n]
      int e = idx + k * 262144;
      int n = e & (NN - 1);
      int q = e >> 11;
      hwT[(size_t)n * OO + q] = hid[(size_t)q * NN + n];
    }
    { int p = idx >> 9, q = idx & (OO - 1);         // iewT[p][q] = iew[q][p], diag 0
      iewT[idx] = (p == q) ? 0.f : iew_in[(size_t)q * OO + p]; }
    tr1[idx] = 0.f;
    if (idx < BB * OO) { tr2[idx]=0.f; tri[idx]=0.f; v2[idx]=0.f; vi[idx]=0.f; }
    #pragma unroll
    for (int k = 0; k < 3; ++k) { int e = idx + k * 262144; if (e < BB*DLY*OO) buf[e]=0.f; }
    if (idx < OO) eiwd[idx] = eiw_in[(size_t)idx * OO + idx];
    if (idx < 2*OO) { ml2[idx]=0.f; minh[idx]=0.f; m2s[idx]=0.f; m3s[idx]=0.f; }
    if (idx < OO) {                                 // cols slot0 = masked row-sums of iew_in
      float sacc = 0.f;
      for (int p = 0; p < OO; ++p) if (p != idx) sacc += iew_in[(size_t)idx * OO + p];
      cols[idx] = sacc; cols[OO + idx] = 0.f;
    }
  }
}

// ---------------------------------------------------------------------------
// K1(t): blocks [0,128): per-batch O-path. Ballot+popc compaction (verified
// in round-1's kLoop), gather unrolled x32 with 4 accumulators — the L2 is
// cold at dispatch start (kernel-boundary acquire invalidates per-XCD L2),
// so the gather is HBM-latency-bound: 32 loads in flight instead of 8.
// Sum order changes are confined to the already-order-free compacted list.
// blocks [128,256): tr1 update from the bitmask (no out re-read).
// ---------------------------------------------------------------------------
__global__ __launch_bounds__(512) void kStep1(
    const int* __restrict__ train_p, float* __restrict__ out,
    uint8_t* __restrict__ ws, int t)
{
#pragma clang fp contract(off)
  const int bx = blockIdx.x, tid = threadIdx.x;
  const int s = t & 1, tm = t % DLY;
  PTRS(ws);
  const int train = *train_p;
  const int se = train ? s : 0;   // eval: cols never cycles, use slot 0

  if (bx < BB) {
    __shared__ unsigned long long sm[32];
    __shared__ int sidx[NN];
    __shared__ short szer[OO];
    __shared__ int scnt, zcnt, anyc;
    const int b = bx, q = tid, lane = tid & 63;
    if (tid == 0) { scnt = 0; zcnt = 0; anyc = 0; }
    if (tid < 32) sm[tid] = mask[((size_t)b * TT + t) * 32 + tid];
    float bv = buf[((size_t)b * DLY + tm) * OO + q];
    float c = cols[se * OO + q];
    __syncthreads();
    if (c != 0.f) anyc = 1;
    // ballot-based compaction: 1 LDS atomic per wave instead of per spike
    #pragma unroll
    for (int k = 0; k < 4; ++k) {
      int n = (k << 9) + tid;
      bool sp = (sm[n >> 6] >> (n & 63)) & 1ull;
      unsigned long long mb = __ballot(sp);
      int base = 0;
      if (lane == 0 && mb) base = atomicAdd(&scnt, __popcll(mb));
      base = __shfl(base, 0, 64);
      if (sp) sidx[base + __popcll(mb & ((1ull << lane) - 1ull))] = n;
    }
    {
      bool z = (bv == 0.f);
      unsigned long long mz = __ballot(z);
      int bz = 0;
      if (lane == 0 && mz) bz = atomicAdd(&zcnt, __popcll(mz));
      bz = __shfl(bz, 0, 64);
      if (z) szer[bz + __popcll(mz & ((1ull << lane) - 1ull))] = (short)q;
    }
    if (train && bx == 0) {                       // cycle double-buffered slots
      cols[(s ^ 1) * OO + q] = 0.f;
      ml2 [(s ^ 1) * OO + q] = 0.f;
      minh[(s ^ 1) * OO + q] = 0.f;
    }
    __syncthreads();
    // l1v[b,q] = sum over spiking n of hwT[n][q] — 32 loads in flight,
    // 4 accumulators (order-free path, absmax-0 verified under reordering)
    float a0 = 0.f, a1 = 0.f, a2 = 0.f, a3 = 0.f;
    { const int cnt = scnt;
      int k = 0;
      for (; k + 32 <= cnt; k += 32) {
        float h[32];
        #pragma unroll
        for (int j = 0; j < 32; ++j) h[j] = hwT[(size_t)sidx[k + j] * OO + q];
        #pragma unroll
        for (int j = 0; j < 8; ++j)   a0 += h[j];
        #pragma unroll
        for (int j = 8; j < 16; ++j)  a1 += h[j];
        #pragma unroll
        for (int j = 16; j < 24; ++j) a2 += h[j];
        #pragma unroll
        for (int j = 24; j < 32; ++j) a3 += h[j];
      }
      for (; k + 8 <= cnt; k += 8) {
        float h[8];
        #pragma unroll
        for (int j = 0; j < 8; ++j) h[j] = hwT[(size_t)sidx[k + j] * OO + q];
        #pragma unroll
        for (int j = 0; j < 8; ++j) a0 += h[j];
      }
      for (; k < cnt; ++k) a0 += hwT[(size_t)sidx[k] * OO + q];
    }
    float l1v = (a0 + a1) + (a2 + a3);
    if (!train) l1v = 0.2f * l1v;
    // inh_out = colsum - sum over buf==0 rows (exactly 0 while iew == 0)
    float inh_o = 0.f;
    if (anyc) {
      float acc2 = c; const int zc = zcnt;
      int k = 0;
      for (; k + 4 <= zc; k += 4) {
        int z0=szer[k], z1=szer[k+1], z2=szer[k+2], z3=szer[k+3];
        acc2 -= iewT[(size_t)z0*OO+q]; acc2 -= iewT[(size_t)z1*OO+q];
        acc2 -= iewT[(size_t)z2*OO+q]; acc2 -= iewT[(size_t)z3*OO+q];
      }
      for (; k < zc; ++k) acc2 -= iewT[(size_t)szer[k]*OO+q];
      inh_o = acc2;
    }
    // l2 neuron (FMA recurrence; margins robust)
    const int bq = b * OO + q;
    float i2  = l1v - inh_o;
    float v2v = fmaf(ALPHA_F, v2[bq], i2);
    bool l2 = (v2v > THRV);
    v2[bq] = l2 ? 0.f : v2v;
    out[(size_t)BB*TT*NN + ((size_t)b * TT + t) * OO + q] = l2 ? 1.f : 0.f;
    // inh neuron: inh_in = l2 * eiw_diag[q]
    float ii  = l2 ? eiwd[q] : 0.f;
    float viv = fmaf(ALPHA_F, vi[bq], ii);
    bool ih = (viv > THRV);
    vi[bq] = ih ? 0.f : viv;
    buf[((size_t)b * DLY + tm) * OO + q] = ih ? 1.f : 0.f;
    if (train) {
      float l2f = l2 ? 1.f : 0.f, ihf = ih ? 1.f : 0.f;
      float d2 = DEC_F * tr2[bq]; tr2[bq] = d2 + OMD_F * l2f;
      float d3 = DEC_F * tri[bq]; tri[bq] = d3 + OMD_F * ihf;
      if (l2) { atomicAdd(&ml2[s * OO + q], 1.f); flags[0] = 1u; }
      if (ih) { atomicAdd(&minh[s * OO + q], 1.f); }
    }
  } else if (train) {
    // tr1 update for batch b from the spike bitmask (sole writer)
    const int b = bx - BB;
    const unsigned long long* mrow = mask + ((size_t)b * TT + t) * 32;
    float* tp = tr1 + (size_t)b * NN;
    #pragma unroll
    for (int k = 0; k < 4; ++k) {
      int n = (k << 9) + tid;
      float l1 = ((mrow[n >> 6] >> (n & 63)) & 1ull) ? 1.f : 0.f;
      float d = DEC_F * tp[n];
      tp[n] = d + OMD_F * l1;
    }
  }
}

// ---------------------------------------------------------------------------
// K2(t): 161 blocks x 512 threads — two 64x64 tiles per block (one per
// 256-thread half; mapping verified in round-1's kLoop). Single wave on 256
// CUs instead of 321-block two-wave. float4 staging + float4 hwT RMW.
// half-slots [0,256): hw tiles; [256,320): iew tiles + next cols;
// half-slot 320: eiw diagonal + mean-state cycling.
// ---------------------------------------------------------------------------
__global__ __launch_bounds__(512) void kStep2(
    const int* __restrict__ train_p, uint8_t* __restrict__ ws, int t)
{
#pragma clang fp contract(off)
  const int bx = blockIdx.x, tid = threadIdx.x;
  const int s = t & 1;
  PTRS(ws);
  if (!*train_p) return;

  __shared__ float s1s[2][BB * 64];
  __shared__ float s2s[2][BB * 64];
  const int hsel = tid >> 8, ltid = tid & 255;
  const int halfId = (bx << 1) + hsel;             // 0..321
  const bool live = (halfId < 320) && (flags[0] != 0u);
  const bool isHW = (halfId < 256);
  const int e  = isHW ? halfId : (halfId - 256);
  const int pt = e >> 3, qt = e & 7;
  float* s1p = s1s[hsel];
  float* s2p = s2s[hsel];
  if (live) {
    const float* Apre = isHW ? tr1 : tri;          // pre-trace slab
    const int preStride = isHW ? NN : OO;
    for (int it = 0; it < 8; ++it) {               // float4 staging
      int ee = (it << 8) + ltid;                   // 2048 float4 = 8192 floats
      int bb = ee >> 4, i = (ee & 15) << 2;
      *(float4*)&s1p[(bb << 6) + i] =
          *(const float4*)&Apre[(size_t)bb * preStride + (pt << 6) + i];
      *(float4*)&s2p[(bb << 6) + i] =
          *(const float4*)&tr2[(bb << 9) + (qt << 6) + i];
    }
  }
  __syncthreads();
  if (live) {
    const int tp = ltid >> 4, tq = ltid & 15;
    float acc[4][4] = {{0.f,0.f,0.f,0.f},{0.f,0.f,0.f,0.f},
                       {0.f,0.f,0.f,0.f},{0.f,0.f,0.f,0.f}};
    for (int b = 0; b < BB; ++b) {
      float4 av = *(const float4*)&s1p[(b << 6) + (tp << 2)];
      float4 cv = *(const float4*)&s2p[(b << 6) + (tq << 2)];
      acc[0][0] = fmaf(av.x, cv.x, acc[0][0]);
      acc[0][1] = fmaf(av.x, cv.y, acc[0][1]);
      acc[0][2] = fmaf(av.x, cv.z, acc[0][2]);
      acc[0][3] = fmaf(av.x, cv.w, acc[0][3]);
      acc[1][0] = fmaf(av.y, cv.x, acc[1][0]);
      acc[1][1] = fmaf(av.y, cv.y, acc[1][1]);
      acc[1][2] = fmaf(av.y, cv.z, acc[1][2]);
      acc[1][3] = fmaf(av.y, cv.w, acc[1][3]);
      acc[2][0] = fmaf(av.z, cv.x, acc[2][0]);
      acc[2][1] = fmaf(av.z, cv.y, acc[2][1]);
      acc[2][2] = fmaf(av.z, cv.z, acc[2][2]);
      acc[2][3] = fmaf(av.z, cv.w, acc[2][3]);
      acc[3][0] = fmaf(av.w, cv.x, acc[3][0]);
      acc[3][1] = fmaf(av.w, cv.y, acc[3][1]);
      acc[3][2] = fmaf(av.w, cv.z, acc[3][2]);
      acc[3][3] = fmaf(av.w, cv.w, acc[3][3]);
    }
    float mq[4];
    #pragma unroll
    for (int j = 0; j < 4; ++j) {      // mean(tr2_t) via exact binary-spike recurrence
      int q = (qt << 6) + (tq << 2) + j;
      mq[j] = DEC_F * m2s[s * OO + q] + OMD_F * (ml2[s * OO + q] * INVB);
    }
    if (isHW) {
      #pragma unroll
      for (int i = 0; i < 4; ++i) {
        size_t p = (size_t)((pt << 6) + (tp << 2) + i);
        float4* hp = (float4*)&hwT[p * OO + (qt << 6) + (tq << 2)];
        float4 o4 = *hp;
        float4 nv;
        nv.x = o4.x + (A_P * (acc[i][0] * INVB) - A_M * o4.x * mq[0]);
        nv.y = o4.y + (A_P * (acc[i][1] * INVB) - A_M * o4.y * mq[1]);
        nv.z = o4.z + (A_P * (acc[i][2] * INVB) - A_M * o4.z * mq[2]);
        nv.w = o4.w + (A_P * (acc[i][3] * INVB) - A_M * o4.w * mq[3]);
        *hp = nv;
      }
    } else {
      float csum[4] = {0.f,0.f,0.f,0.f};
      #pragma unroll
      for (int i = 0; i < 4; ++i) {
        int p = (pt << 6) + (tp << 2) + i;
        #pragma unroll
        for (int j = 0; j < 4; ++j) {
          int q = (qt << 6) + (tq << 2) + j;
          float* wp = &iewT[(size_t)p * OO + q];
          float oldv = *wp;
          float nv = (p == q) ? 0.f
                              : (oldv + (A_P * (acc[i][j] * INVB) - A_M * oldv * mq[j]));
          *wp = nv;
          csum[j] += nv;
        }
      }
      #pragma unroll
      for (int j = 0; j < 4; ++j)
        atomicAdd(&cols[(s ^ 1) * OO + ((qt << 6) + (tq << 2) + j)], csum[j]);
    }
  } else if (halfId == 320) {
    // eiw diagonal + mean-state slot cycling (runs every step)
    for (int k = 0; k < 2; ++k) {
      int q = (k << 8) + ltid;
      float m2v = DEC_F * m2s[s*OO+q] + OMD_F * (ml2[s*OO+q] * INVB);
      float m3v = DEC_F * m3s[s*OO+q] + OMD_F * (minh[s*OO+q] * INVB);
      m2s[(s^1)*OO+q] = m2v;
      m3s[(s^1)*OO+q] = m3v;
      float hd = 0.f;
      for (int b = 0; b < BB; ++b) hd = fmaf(tri[b*OO+q], tr2[b*OO+q], hd);
      hd *= INVB;
      float oldv = eiwd[q];
      eiwd[q] = oldv + (A_P * hd - A_M * oldv * m3v);
    }
  }
}

extern "C" void kernel_launch(void* const* d_in, const int* in_sizes, int n_in,
                              void* d_out, int out_size, void* d_ws, size_t ws_size,
                              hipStream_t stream) {
  const float* x     = (const float*)d_in[0];
  const float* w_in  = (const float*)d_in[1];
  const float* hid   = (const float*)d_in[2];
  const float* eiw   = (const float*)d_in[3];
  const float* iew   = (const float*)d_in[4];
  const int*   train = (const int*)d_in[5];
  float* out = (float*)d_out;
  uint8_t* ws = (uint8_t*)d_ws;
  (void)in_sizes; (void)n_in; (void)out_size; (void)ws_size;

  hipLaunchKernelGGL(kZ, dim3(1), dim3(64), 0, stream, ws);
  hipLaunchKernelGGL(kA, dim3(2048), dim3(256), 0, stream, x, w_in, hid, eiw, iew, out, ws);
  for (int t = 0; t < TT; ++t) {
    hipLaunchKernelGGL(kStep1, dim3(256), dim3(512), 0, stream, train, out, ws, t);
    hipLaunchKernelGGL(kStep2, dim3(161), dim3(512), 0, stream, train, ws, t);
  }
}